// Round 2
// baseline (9368.877 us; speedup 1.0000x reference)
//
#include <hip/hip_runtime.h>

typedef __attribute__((ext_vector_type(8))) short short8;
typedef __attribute__((ext_vector_type(4))) float f32x4;

#define T_   512
#define B_   64
#define I_   256
#define H_   512
#define BH   (B_*H_)   // 32768
#define NBLK 32

// ---- ws layout (bytes) ----
#define WS_XB   0u            // bf16 X        [512][64][256]   16,777,216
#define WS_HS   16777216u     // bf16 hs ring  [513][64][512]   33,619,968
#define WS_H1   50397184u     // bf16 h1 dbuf  [2][64][512]        131,072
#define WS_P0   50528256u     // packed W0cat  (3 MB)
#define WS_P1   53673984u     // packed W1cat  (4 MB)
#define WS_B0   57868288u     // f32 bias0 [2048]
#define WS_B1   57876480u     // f32 bias1 [2048]
#define WS_BAR  57884672u     // unsigned barrier counter

__device__ __forceinline__ unsigned short f2b(float f) {
    unsigned int x = __builtin_bit_cast(unsigned int, f);
    unsigned int r = (x + 0x7fffu + ((x >> 16) & 1u)) >> 16;   // RNE
    return (unsigned short)r;
}

// X f32 -> bf16, and copy inputs to output tail (outputs: h_n|c_n|inputs)
__global__ void convert_x(const float* __restrict__ X, unsigned short* __restrict__ Xb,
                          float* __restrict__ outcpy) {
    const int n4 = (T_ * B_ * I_) / 4;
    for (int i = blockIdx.x * blockDim.x + threadIdx.x; i < n4; i += gridDim.x * blockDim.x) {
        float4 v = reinterpret_cast<const float4*>(X)[i];
        ushort4 u;
        u.x = f2b(v.x); u.y = f2b(v.y); u.z = f2b(v.z); u.w = f2b(v.w);
        reinterpret_cast<ushort4*>(Xb)[i] = u;
        reinterpret_cast<float4*>(outcpy)[i] = v;
    }
}

// Pack Wcat0 = [Wih0 | Whh0] (K=768) into 16x16x32 B-fragment order.
// p0[(((j*4+g)*24+ks)*64 + lane)*8 + e] = Wcat0[g*512 + j*16 + (lane&15)][ks*32 + (lane>>4)*8 + e]
__global__ void pack_w0(const float* __restrict__ Wih, const float* __restrict__ Whh,
                        unsigned short* __restrict__ p0) {
    const int n = 32 * 4 * 24 * 64;
    int idx = blockIdx.x * blockDim.x + threadIdx.x;
    if (idx >= n) return;
    int lane = idx & 63; int q = idx >> 6;
    int ks = q % 24; q /= 24;
    int g = q & 3;   int j = q >> 2;
    int row_w = g * 512 + j * 16 + (lane & 15);
    int k0 = ks * 32 + (lane >> 4) * 8;
    short8 o;
#pragma unroll
    for (int e = 0; e < 8; e++) {
        int k = k0 + e;
        float v = (k < 256) ? Wih[row_w * 256 + k] : Whh[row_w * 512 + (k - 256)];
        o[e] = (short)f2b(v);
    }
    reinterpret_cast<short8*>(p0)[idx] = o;
}

// Wcat1 = [Wih1 | Whh1] (K=1024), 32 k-steps
__global__ void pack_w1(const float* __restrict__ Wih, const float* __restrict__ Whh,
                        unsigned short* __restrict__ p1) {
    const int n = 32 * 4 * 32 * 64;
    int idx = blockIdx.x * blockDim.x + threadIdx.x;
    if (idx >= n) return;
    int lane = idx & 63; int q = idx >> 6;
    int ks = q & 31; q >>= 5;
    int g = q & 3;   int j = q >> 2;
    int row_w = g * 512 + j * 16 + (lane & 15);
    int k0 = ks * 32 + (lane >> 4) * 8;
    short8 o;
#pragma unroll
    for (int e = 0; e < 8; e++) {
        int k = k0 + e;
        float v = (k < 512) ? Wih[row_w * 512 + k] : Whh[row_w * 512 + (k - 512)];
        o[e] = (short)f2b(v);
    }
    reinterpret_cast<short8*>(p1)[idx] = o;
}

// combined biases + initial h states (bf16) + barrier counter zero
__global__ void prep_misc(const float* __restrict__ bih0, const float* __restrict__ bhh0,
                          const float* __restrict__ bih1, const float* __restrict__ bhh1,
                          const float* __restrict__ h0,
                          float* __restrict__ b0c, float* __restrict__ b1c,
                          unsigned short* __restrict__ hs, unsigned short* __restrict__ h1b,
                          unsigned* __restrict__ bar) {
    int i = blockIdx.x * blockDim.x + threadIdx.x;
    if (i == 0) __hip_atomic_store(bar, 0u, __ATOMIC_RELAXED, __HIP_MEMORY_SCOPE_AGENT);
    if (i < 2048) b0c[i] = bih0[i] + bhh0[i];
    else if (i < 4096) { int k = i - 2048; b1c[k] = bih1[k] + bhh1[k]; }
    else if (i < 4096 + BH) { int k = i - 4096; hs[k] = f2b(h0[k]); }
    else if (i < 4096 + 2 * BH) { int k = i - 4096 - BH; h1b[k] = f2b(h0[BH + k]); }
}

// grid barrier: monotonic counter, release-arrive / acquire-spin (ockl grid_sync pattern)
__device__ __forceinline__ void gridbar(unsigned* bar, unsigned target) {
    __syncthreads();
    if (threadIdx.x == 0) {
        __threadfence();
        __hip_atomic_fetch_add(bar, 1u, __ATOMIC_RELAXED, __HIP_MEMORY_SCOPE_AGENT);
        while (__hip_atomic_load(bar, __ATOMIC_RELAXED, __HIP_MEMORY_SCOPE_AGENT) < target) {
            __builtin_amdgcn_s_sleep(2);
        }
        __threadfence();
    }
    __syncthreads();
}

// Persistent LSTM: 32 blocks x 256 threads (regular launch + software grid barrier).
// Block j owns h-cols [j*16, j*16+16). Wave w owns rows [w*16, w*16+16), all 4 gates.
// Lane holds i,f,g,o for its (row,hc) in registers -> fully in-register epilogue.
__global__ void __launch_bounds__(256, 1) lstm_pers(
    const unsigned short* __restrict__ Xb,
    unsigned short* __restrict__ hs,
    unsigned short* __restrict__ h1b,
    const unsigned short* __restrict__ p0,
    const unsigned short* __restrict__ p1,
    const float* __restrict__ b0c,
    const float* __restrict__ b1c,
    const float* __restrict__ c0,
    float* __restrict__ out,
    unsigned* __restrict__ bar) {
    __shared__ __align__(16) unsigned short bsh[65536];   // 128 KB packed-W slice

    const int j = blockIdx.x;
    const int tid = threadIdx.x;
    const int lane = tid & 63;
    const int w = tid >> 6;
    const int la = lane & 15;      // A-row / B-col / D-col within tile
    const int lk = lane >> 4;      // k-subgroup (0..3); D-rows = lk*4+reg
    const int hc = la;
    unsigned gen = 0;

    // ---------------- phase A : layer 0 (K = 256 x + 512 h = 24 ksteps) ----------------
    {
        const short8* src = reinterpret_cast<const short8*>(p0 + (size_t)j * 49152);
        short8* dst = reinterpret_cast<short8*>(bsh);
        for (int i = tid; i < 6144; i += 256) dst[i] = src[i];
    }
    __syncthreads();

    float bi = b0c[       j * 16 + hc];
    float bf = b0c[512  + j * 16 + hc];
    float bg = b0c[1024 + j * 16 + hc];
    float bo = b0c[1536 + j * 16 + hc];
    float c[4];
#pragma unroll
    for (int r = 0; r < 4; r++) c[r] = c0[(w * 16 + lk * 4 + r) * 512 + j * 16 + hc];

    for (int t = 0; t < T_; t++) {
        f32x4 a0 = {0.f,0.f,0.f,0.f}, a1 = a0, a2 = a0, a3 = a0;
        const unsigned short* Arow_x = Xb + ((size_t)t * B_ + w * 16 + la) * 256 + lk * 8;
        const unsigned short* Arow_h = hs + (size_t)t * BH + (size_t)(w * 16 + la) * 512 + lk * 8;
#pragma unroll
        for (int ks = 0; ks < 24; ks++) {
            short8 av;
            if (ks < 8) av = *reinterpret_cast<const short8*>(Arow_x + ks * 32);
            else        av = *reinterpret_cast<const short8*>(Arow_h + (ks - 8) * 32);
            const unsigned short* bb = bsh + ks * 512 + lane * 8;
            a0 = __builtin_amdgcn_mfma_f32_16x16x32_bf16(av, *reinterpret_cast<const short8*>(bb            ), a0, 0, 0, 0);
            a1 = __builtin_amdgcn_mfma_f32_16x16x32_bf16(av, *reinterpret_cast<const short8*>(bb + 24 * 512), a1, 0, 0, 0);
            a2 = __builtin_amdgcn_mfma_f32_16x16x32_bf16(av, *reinterpret_cast<const short8*>(bb + 48 * 512), a2, 0, 0, 0);
            a3 = __builtin_amdgcn_mfma_f32_16x16x32_bf16(av, *reinterpret_cast<const short8*>(bb + 72 * 512), a3, 0, 0, 0);
        }
#pragma unroll
        for (int r = 0; r < 4; r++) {
            float ip = a0[r] + bi, fp = a1[r] + bf, gp = a2[r] + bg, op = a3[r] + bo;
            float si = 1.f / (1.f + __expf(-ip));
            float sf = 1.f / (1.f + __expf(-fp));
            float so = 1.f / (1.f + __expf(-op));
            float tg = tanhf(gp);
            float cn = sf * c[r] + si * tg;
            float hn = so * tanhf(cn);
            c[r] = cn;
            int row = w * 16 + lk * 4 + r;
            hs[(size_t)(t + 1) * BH + row * 512 + j * 16 + hc] = f2b(hn);
            if (t == T_ - 1) {
                out[row * 512 + j * 16 + hc] = hn;            // h_n[0]
                out[65536 + row * 512 + j * 16 + hc] = cn;    // c_n[0]
            }
        }
        ++gen;
        gridbar(bar, gen * NBLK);
    }

    // ---------------- phase B : layer 1 (K = 512 h0 + 512 h1 = 32 ksteps) ----------------
    {
        const short8* src = reinterpret_cast<const short8*>(p1 + (size_t)j * 65536);
        short8* dst = reinterpret_cast<short8*>(bsh);
        for (int i = tid; i < 8192; i += 256) dst[i] = src[i];
    }
    __syncthreads();

    bi = b1c[       j * 16 + hc];
    bf = b1c[512  + j * 16 + hc];
    bg = b1c[1024 + j * 16 + hc];
    bo = b1c[1536 + j * 16 + hc];
#pragma unroll
    for (int r = 0; r < 4; r++) c[r] = c0[BH + (w * 16 + lk * 4 + r) * 512 + j * 16 + hc];

    for (int t = 0; t < T_; t++) {
        f32x4 a0 = {0.f,0.f,0.f,0.f}, a1 = a0, a2 = a0, a3 = a0;
        const unsigned short* Arow_x = hs + (size_t)(t + 1) * BH + (size_t)(w * 16 + la) * 512 + lk * 8;
        const unsigned short* Arow_h = h1b + (size_t)(t & 1) * BH + (size_t)(w * 16 + la) * 512 + lk * 8;
#pragma unroll
        for (int ks = 0; ks < 32; ks++) {
            short8 av;
            if (ks < 16) av = *reinterpret_cast<const short8*>(Arow_x + ks * 32);
            else         av = *reinterpret_cast<const short8*>(Arow_h + (ks - 16) * 32);
            const unsigned short* bb = bsh + ks * 512 + lane * 8;
            a0 = __builtin_amdgcn_mfma_f32_16x16x32_bf16(av, *reinterpret_cast<const short8*>(bb            ), a0, 0, 0, 0);
            a1 = __builtin_amdgcn_mfma_f32_16x16x32_bf16(av, *reinterpret_cast<const short8*>(bb + 32 * 512), a1, 0, 0, 0);
            a2 = __builtin_amdgcn_mfma_f32_16x16x32_bf16(av, *reinterpret_cast<const short8*>(bb + 64 * 512), a2, 0, 0, 0);
            a3 = __builtin_amdgcn_mfma_f32_16x16x32_bf16(av, *reinterpret_cast<const short8*>(bb + 96 * 512), a3, 0, 0, 0);
        }
#pragma unroll
        for (int r = 0; r < 4; r++) {
            float ip = a0[r] + bi, fp = a1[r] + bf, gp = a2[r] + bg, op = a3[r] + bo;
            float si = 1.f / (1.f + __expf(-ip));
            float sf = 1.f / (1.f + __expf(-fp));
            float so = 1.f / (1.f + __expf(-op));
            float tg = tanhf(gp);
            float cn = sf * c[r] + si * tg;
            float hn = so * tanhf(cn);
            c[r] = cn;
            int row = w * 16 + lk * 4 + r;
            h1b[(size_t)((t + 1) & 1) * BH + row * 512 + j * 16 + hc] = f2b(hn);
            if (t == T_ - 1) {
                out[BH + row * 512 + j * 16 + hc] = hn;            // h_n[1]
                out[65536 + BH + row * 512 + j * 16 + hc] = cn;    // c_n[1]
            }
        }
        ++gen;
        gridbar(bar, gen * NBLK);
    }
}

extern "C" void kernel_launch(void* const* d_in, const int* in_sizes, int n_in,
                              void* d_out, int out_size, void* d_ws, size_t ws_size,
                              hipStream_t stream) {
    const float* X    = (const float*)d_in[0];
    const float* h0   = (const float*)d_in[1];
    const float* c0   = (const float*)d_in[2];
    const float* wih0 = (const float*)d_in[3];
    const float* whh0 = (const float*)d_in[4];
    const float* bih0 = (const float*)d_in[5];
    const float* bhh0 = (const float*)d_in[6];
    const float* wih1 = (const float*)d_in[7];
    const float* whh1 = (const float*)d_in[8];
    const float* bih1 = (const float*)d_in[9];
    const float* bhh1 = (const float*)d_in[10];
    float* out = (float*)d_out;
    char* ws = (char*)d_ws;

    unsigned short* Xb  = (unsigned short*)(ws + WS_XB);
    unsigned short* hsb = (unsigned short*)(ws + WS_HS);
    unsigned short* h1b = (unsigned short*)(ws + WS_H1);
    unsigned short* p0  = (unsigned short*)(ws + WS_P0);
    unsigned short* p1  = (unsigned short*)(ws + WS_P1);
    float* b0c = (float*)(ws + WS_B0);
    float* b1c = (float*)(ws + WS_B1);
    unsigned* bar = (unsigned*)(ws + WS_BAR);

    hipLaunchKernelGGL(convert_x, dim3(2048), dim3(256), 0, stream, X, Xb, out + 131072);
    hipLaunchKernelGGL(pack_w0, dim3(768), dim3(256), 0, stream, wih0, whh0, p0);
    hipLaunchKernelGGL(pack_w1, dim3(1024), dim3(256), 0, stream, wih1, whh1, p1);
    hipLaunchKernelGGL(prep_misc, dim3(276), dim3(256), 0, stream,
                       bih0, bhh0, bih1, bhh1, h0, b0c, b1c, hsb, h1b, bar);
    hipLaunchKernelGGL(lstm_pers, dim3(NBLK), dim3(256), 0, stream,
                       Xb, hsb, h1b, p0, p1, b0c, b1c, c0, out, bar);
}

// Round 3
// 5578.794 us; speedup vs baseline: 1.6794x; 1.6794x over previous
//
#include <hip/hip_runtime.h>

typedef __attribute__((ext_vector_type(8))) short short8;
typedef __attribute__((ext_vector_type(4))) float f32x4;

#define T_   512
#define B_   64
#define I_   256
#define H_   512
#define BH   (B_*H_)   // 32768
#define NB0  32
#define NBT  64        // total blocks in barrier

// ---- ws layout (bytes) ----
#define WS_XB   0u            // bf16 X        [512][64][256]   16,777,216
#define WS_HS   16777216u     // bf16 hs ring  [513][64][512]   33,619,968
#define WS_H1   50397184u     // bf16 h1 dbuf  [2][64][512]        131,072
#define WS_P0   50528256u     // packed W0cat  (3 MB)
#define WS_P1   53673984u     // packed W1cat  (4 MB)
#define WS_B0   57868288u     // f32 bias0 [2048]
#define WS_B1   57876480u     // f32 bias1 [2048]
#define WS_BAR  57884672u     // 4 x unsigned counters, 64B apart

__device__ __forceinline__ unsigned short f2b(float f) {
    unsigned int x = __builtin_bit_cast(unsigned int, f);
    unsigned int r = (x + 0x7fffu + ((x >> 16) & 1u)) >> 16;   // RNE
    return (unsigned short)r;
}

// X f32 -> bf16, and copy inputs to output tail (outputs: h_n|c_n|inputs)
__global__ void convert_x(const float* __restrict__ X, unsigned short* __restrict__ Xb,
                          float* __restrict__ outcpy) {
    const int n4 = (T_ * B_ * I_) / 4;
    for (int i = blockIdx.x * blockDim.x + threadIdx.x; i < n4; i += gridDim.x * blockDim.x) {
        float4 v = reinterpret_cast<const float4*>(X)[i];
        ushort4 u;
        u.x = f2b(v.x); u.y = f2b(v.y); u.z = f2b(v.z); u.w = f2b(v.w);
        reinterpret_cast<ushort4*>(Xb)[i] = u;
        reinterpret_cast<float4*>(outcpy)[i] = v;
    }
}

// Pack Wcat0 = [Wih0 | Whh0] (K=768) into 16x16x32 B-fragment order.
// p0[(((j*4+g)*24+ks)*64 + lane)*8 + e] = Wcat0[g*512 + j*16 + (lane&15)][ks*32 + (lane>>4)*8 + e]
__global__ void pack_w0(const float* __restrict__ Wih, const float* __restrict__ Whh,
                        unsigned short* __restrict__ p0) {
    const int n = 32 * 4 * 24 * 64;
    int idx = blockIdx.x * blockDim.x + threadIdx.x;
    if (idx >= n) return;
    int lane = idx & 63; int q = idx >> 6;
    int ks = q % 24; q /= 24;
    int g = q & 3;   int j = q >> 2;
    int row_w = g * 512 + j * 16 + (lane & 15);
    int k0 = ks * 32 + (lane >> 4) * 8;
    short8 o;
#pragma unroll
    for (int e = 0; e < 8; e++) {
        int k = k0 + e;
        float v = (k < 256) ? Wih[row_w * 256 + k] : Whh[row_w * 512 + (k - 256)];
        o[e] = (short)f2b(v);
    }
    reinterpret_cast<short8*>(p0)[idx] = o;
}

// Wcat1 = [Wih1 | Whh1] (K=1024), 32 k-steps
__global__ void pack_w1(const float* __restrict__ Wih, const float* __restrict__ Whh,
                        unsigned short* __restrict__ p1) {
    const int n = 32 * 4 * 32 * 64;
    int idx = blockIdx.x * blockDim.x + threadIdx.x;
    if (idx >= n) return;
    int lane = idx & 63; int q = idx >> 6;
    int ks = q & 31; q >>= 5;
    int g = q & 3;   int j = q >> 2;
    int row_w = g * 512 + j * 16 + (lane & 15);
    int k0 = ks * 32 + (lane >> 4) * 8;
    short8 o;
#pragma unroll
    for (int e = 0; e < 8; e++) {
        int k = k0 + e;
        float v = (k < 512) ? Wih[row_w * 512 + k] : Whh[row_w * 512 + (k - 512)];
        o[e] = (short)f2b(v);
    }
    reinterpret_cast<short8*>(p1)[idx] = o;
}

// combined biases + initial h states (bf16) + barrier counters zero
__global__ void prep_misc(const float* __restrict__ bih0, const float* __restrict__ bhh0,
                          const float* __restrict__ bih1, const float* __restrict__ bhh1,
                          const float* __restrict__ h0,
                          float* __restrict__ b0c, float* __restrict__ b1c,
                          unsigned short* __restrict__ hs, unsigned short* __restrict__ h1b,
                          unsigned* __restrict__ bar) {
    int i = blockIdx.x * blockDim.x + threadIdx.x;
    if (i < 64) __hip_atomic_store(&bar[i], 0u, __ATOMIC_RELAXED, __HIP_MEMORY_SCOPE_AGENT);
    if (i < 2048) b0c[i] = bih0[i] + bhh0[i];
    else if (i < 4096) { int k = i - 2048; b1c[k] = bih1[k] + bhh1[k]; }
    else if (i < 4096 + BH) { int k = i - 4096; hs[k] = f2b(h0[k]); }
    else if (i < 4096 + 2 * BH) { int k = i - 4096 - BH; h1b[k] = f2b(h0[BH + k]); }
}

// ---- split-counter grid barrier (proven round-2 fence pattern) ----
__device__ __forceinline__ void bar_arrive(unsigned* bar, int slot) {
    __syncthreads();                      // all waves' stores drained (vmcnt(0) at s_barrier)
    if (threadIdx.x == 0) {
        __threadfence();                  // release: L2 writeback for cross-XCD visibility
        __hip_atomic_fetch_add(&bar[slot * 16], 1u, __ATOMIC_RELAXED, __HIP_MEMORY_SCOPE_AGENT);
    }
}
__device__ __forceinline__ void bar_wait(unsigned* bar, unsigned target) {
    if (threadIdx.x == 0) {
        for (;;) {
            unsigned s = 0;
#pragma unroll
            for (int i = 0; i < 4; i++)
                s += __hip_atomic_load(&bar[i * 16], __ATOMIC_RELAXED, __HIP_MEMORY_SCOPE_AGENT);
            if (s >= target) break;
            __builtin_amdgcn_s_sleep(1);
        }
        __threadfence();                  // acquire: invalidate
    }
    __syncthreads();
}

// Persistent pipelined LSTM: 64 blocks x 256 threads.
// Blocks 0..31: layer 0 (block j owns h-cols j*16..+15). Blocks 32..63: layer 1, one step behind.
// Wave w owns rows w*16..+15, all 4 gates; lane holds i,f,g,o for its (row,hc) in registers.
__global__ void __launch_bounds__(256, 1) lstm_pers(
    const unsigned short* __restrict__ Xb,
    unsigned short* __restrict__ hs,
    unsigned short* __restrict__ h1b,
    const unsigned short* __restrict__ p0,
    const unsigned short* __restrict__ p1,
    const float* __restrict__ b0c,
    const float* __restrict__ b1c,
    const float* __restrict__ c0,
    float* __restrict__ out,
    unsigned* __restrict__ bar) {
    __shared__ __align__(16) unsigned short bsh[65536];   // up to 128 KB packed-W slice

    const int bid = blockIdx.x;
    const int tid = threadIdx.x;
    const int lane = tid & 63;
    const int w = tid >> 6;
    const int la = lane & 15;      // A-row / D-col within tile
    const int lk = lane >> 4;      // k-subgroup; D-rows = lk*4+reg
    const int hc = la;
    const int slot = bid & 3;

    if (bid < NB0) {
        // ================= layer 0 =================
        const int j = bid;
        {
            const short8* src = reinterpret_cast<const short8*>(p0 + (size_t)j * 49152);
            short8* dst = reinterpret_cast<short8*>(bsh);
            for (int i = tid; i < 6144; i += 256) dst[i] = src[i];
        }
        __syncthreads();

        const float bi = b0c[       j * 16 + hc];
        const float bf = b0c[512  + j * 16 + hc];
        const float bg = b0c[1024 + j * 16 + hc];
        const float bo = b0c[1536 + j * 16 + hc];
        float c[4];
#pragma unroll
        for (int r = 0; r < 4; r++) c[r] = c0[(w * 16 + lk * 4 + r) * 512 + j * 16 + hc];

        // initial x-part for step 0 (no barrier needed)
        f32x4 a0 = {0.f,0.f,0.f,0.f}, a1 = a0, a2 = a0, a3 = a0;
        {
            const unsigned short* Arow_x = Xb + (size_t)(0 * B_ + w * 16 + la) * 256 + lk * 8;
#pragma unroll
            for (int ks = 0; ks < 8; ks++) {
                short8 av = *reinterpret_cast<const short8*>(Arow_x + ks * 32);
                const unsigned short* bb = bsh + ks * 512 + lane * 8;
                a0 = __builtin_amdgcn_mfma_f32_16x16x32_bf16(av, *reinterpret_cast<const short8*>(bb            ), a0, 0, 0, 0);
                a1 = __builtin_amdgcn_mfma_f32_16x16x32_bf16(av, *reinterpret_cast<const short8*>(bb + 24 * 512), a1, 0, 0, 0);
                a2 = __builtin_amdgcn_mfma_f32_16x16x32_bf16(av, *reinterpret_cast<const short8*>(bb + 48 * 512), a2, 0, 0, 0);
                a3 = __builtin_amdgcn_mfma_f32_16x16x32_bf16(av, *reinterpret_cast<const short8*>(bb + 72 * 512), a3, 0, 0, 0);
            }
        }

        for (int n = 0; n < T_; n++) {
            if (n > 0) bar_wait(bar, (unsigned)NBT * n);
            // critical h-part: K=512 over hs[n]
            const unsigned short* Arow_h = hs + (size_t)n * BH + (size_t)(w * 16 + la) * 512 + lk * 8;
#pragma unroll
            for (int ks = 0; ks < 16; ks++) {
                short8 av = *reinterpret_cast<const short8*>(Arow_h + ks * 32);
                const unsigned short* bb = bsh + (8 + ks) * 512 + lane * 8;
                a0 = __builtin_amdgcn_mfma_f32_16x16x32_bf16(av, *reinterpret_cast<const short8*>(bb            ), a0, 0, 0, 0);
                a1 = __builtin_amdgcn_mfma_f32_16x16x32_bf16(av, *reinterpret_cast<const short8*>(bb + 24 * 512), a1, 0, 0, 0);
                a2 = __builtin_amdgcn_mfma_f32_16x16x32_bf16(av, *reinterpret_cast<const short8*>(bb + 48 * 512), a2, 0, 0, 0);
                a3 = __builtin_amdgcn_mfma_f32_16x16x32_bf16(av, *reinterpret_cast<const short8*>(bb + 72 * 512), a3, 0, 0, 0);
            }
#pragma unroll
            for (int r = 0; r < 4; r++) {
                float ip = a0[r] + bi, fp = a1[r] + bf, gp = a2[r] + bg, op = a3[r] + bo;
                float si = 1.f / (1.f + __expf(-ip));
                float sf = 1.f / (1.f + __expf(-fp));
                float so = 1.f / (1.f + __expf(-op));
                float tg = tanhf(gp);
                float cn = sf * c[r] + si * tg;
                float hn = so * tanhf(cn);
                c[r] = cn;
                int row = w * 16 + lk * 4 + r;
                hs[(size_t)(n + 1) * BH + row * 512 + j * 16 + hc] = f2b(hn);
                if (n == T_ - 1) {
                    out[row * 512 + j * 16 + hc] = hn;            // h_n[0]
                    out[65536 + row * 512 + j * 16 + hc] = cn;    // c_n[0]
                }
            }
            bar_arrive(bar, slot);
            if (n < T_ - 1) {   // hidden x-part for step n+1, overlaps other blocks' arrivals
                f32x4 z = {0.f,0.f,0.f,0.f};
                a0 = z; a1 = z; a2 = z; a3 = z;
                const unsigned short* Arow_x = Xb + ((size_t)(n + 1) * B_ + w * 16 + la) * 256 + lk * 8;
#pragma unroll
                for (int ks = 0; ks < 8; ks++) {
                    short8 av = *reinterpret_cast<const short8*>(Arow_x + ks * 32);
                    const unsigned short* bb = bsh + ks * 512 + lane * 8;
                    a0 = __builtin_amdgcn_mfma_f32_16x16x32_bf16(av, *reinterpret_cast<const short8*>(bb            ), a0, 0, 0, 0);
                    a1 = __builtin_amdgcn_mfma_f32_16x16x32_bf16(av, *reinterpret_cast<const short8*>(bb + 24 * 512), a1, 0, 0, 0);
                    a2 = __builtin_amdgcn_mfma_f32_16x16x32_bf16(av, *reinterpret_cast<const short8*>(bb + 48 * 512), a2, 0, 0, 0);
                    a3 = __builtin_amdgcn_mfma_f32_16x16x32_bf16(av, *reinterpret_cast<const short8*>(bb + 72 * 512), a3, 0, 0, 0);
                }
            }
        }
    } else {
        // ================= layer 1 (one step behind) =================
        const int j = bid - NB0;
        {
            const short8* src = reinterpret_cast<const short8*>(p1 + (size_t)j * 65536);
            short8* dst = reinterpret_cast<short8*>(bsh);
            for (int i = tid; i < 8192; i += 256) dst[i] = src[i];
        }
        __syncthreads();

        const float bi = b1c[       j * 16 + hc];
        const float bf = b1c[512  + j * 16 + hc];
        const float bg = b1c[1024 + j * 16 + hc];
        const float bo = b1c[1536 + j * 16 + hc];
        float c[4];
#pragma unroll
        for (int r = 0; r < 4; r++) c[r] = c0[BH + (w * 16 + lk * 4 + r) * 512 + j * 16 + hc];

#define L1_STEP(s, FINAL)                                                                              \
        {                                                                                              \
            f32x4 z = {0.f,0.f,0.f,0.f};                                                               \
            f32x4 a0 = z, a1 = z, a2 = z, a3 = z;                                                      \
            const unsigned short* Arow_x = hs + (size_t)((s) + 1) * BH + (size_t)(w * 16 + la) * 512 + lk * 8; \
            const unsigned short* Arow_h = h1b + (size_t)((s) & 1) * BH + (size_t)(w * 16 + la) * 512 + lk * 8; \
            _Pragma("unroll")                                                                          \
            for (int ks = 0; ks < 32; ks++) {                                                          \
                short8 av;                                                                             \
                if (ks < 16) av = *reinterpret_cast<const short8*>(Arow_x + ks * 32);                  \
                else         av = *reinterpret_cast<const short8*>(Arow_h + (ks - 16) * 32);           \
                const unsigned short* bb = bsh + ks * 512 + lane * 8;                                  \
                a0 = __builtin_amdgcn_mfma_f32_16x16x32_bf16(av, *reinterpret_cast<const short8*>(bb            ), a0, 0, 0, 0); \
                a1 = __builtin_amdgcn_mfma_f32_16x16x32_bf16(av, *reinterpret_cast<const short8*>(bb + 32 * 512), a1, 0, 0, 0); \
                a2 = __builtin_amdgcn_mfma_f32_16x16x32_bf16(av, *reinterpret_cast<const short8*>(bb + 64 * 512), a2, 0, 0, 0); \
                a3 = __builtin_amdgcn_mfma_f32_16x16x32_bf16(av, *reinterpret_cast<const short8*>(bb + 96 * 512), a3, 0, 0, 0); \
            }                                                                                          \
            _Pragma("unroll")                                                                          \
            for (int r = 0; r < 4; r++) {                                                              \
                float ip = a0[r] + bi, fp = a1[r] + bf, gp = a2[r] + bg, op = a3[r] + bo;              \
                float si = 1.f / (1.f + __expf(-ip));                                                  \
                float sf = 1.f / (1.f + __expf(-fp));                                                  \
                float so = 1.f / (1.f + __expf(-op));                                                  \
                float tg = tanhf(gp);                                                                  \
                float cn = sf * c[r] + si * tg;                                                        \
                float hn = so * tanhf(cn);                                                             \
                c[r] = cn;                                                                             \
                int row = w * 16 + lk * 4 + r;                                                         \
                if (!(FINAL)) {                                                                        \
                    h1b[(size_t)(((s) + 1) & 1) * BH + row * 512 + j * 16 + hc] = f2b(hn);             \
                } else {                                                                               \
                    out[BH + row * 512 + j * 16 + hc] = hn;                                            \
                    out[65536 + BH + row * 512 + j * 16 + hc] = cn;                                    \
                }                                                                                      \
            }                                                                                          \
        }

        for (int n = 0; n < T_; n++) {
            if (n > 0) {
                bar_wait(bar, (unsigned)NBT * n);
                L1_STEP(n - 1, 0)
            }
            bar_arrive(bar, slot);
        }
        // tail: s = 511
        bar_wait(bar, (unsigned)NBT * T_);
        L1_STEP(T_ - 1, 1)
    }
}

extern "C" void kernel_launch(void* const* d_in, const int* in_sizes, int n_in,
                              void* d_out, int out_size, void* d_ws, size_t ws_size,
                              hipStream_t stream) {
    const float* X    = (const float*)d_in[0];
    const float* h0   = (const float*)d_in[1];
    const float* c0   = (const float*)d_in[2];
    const float* wih0 = (const float*)d_in[3];
    const float* whh0 = (const float*)d_in[4];
    const float* bih0 = (const float*)d_in[5];
    const float* bhh0 = (const float*)d_in[6];
    const float* wih1 = (const float*)d_in[7];
    const float* whh1 = (const float*)d_in[8];
    const float* bih1 = (const float*)d_in[9];
    const float* bhh1 = (const float*)d_in[10];
    float* out = (float*)d_out;
    char* ws = (char*)d_ws;

    unsigned short* Xb  = (unsigned short*)(ws + WS_XB);
    unsigned short* hsb = (unsigned short*)(ws + WS_HS);
    unsigned short* h1b = (unsigned short*)(ws + WS_H1);
    unsigned short* p0  = (unsigned short*)(ws + WS_P0);
    unsigned short* p1  = (unsigned short*)(ws + WS_P1);
    float* b0c = (float*)(ws + WS_B0);
    float* b1c = (float*)(ws + WS_B1);
    unsigned* bar = (unsigned*)(ws + WS_BAR);

    hipLaunchKernelGGL(convert_x, dim3(2048), dim3(256), 0, stream, X, Xb, out + 131072);
    hipLaunchKernelGGL(pack_w0, dim3(768), dim3(256), 0, stream, wih0, whh0, p0);
    hipLaunchKernelGGL(pack_w1, dim3(1024), dim3(256), 0, stream, wih1, whh1, p1);
    hipLaunchKernelGGL(prep_misc, dim3(276), dim3(256), 0, stream,
                       bih0, bhh0, bih1, bhh1, h0, b0c, b1c, hsb, h1b, bar);
    hipLaunchKernelGGL(lstm_pers, dim3(NBT), dim3(256), 0, stream,
                       Xb, hsb, h1b, p0, p1, b0c, b1c, c0, out, bar);
}

// Round 4
// 4059.441 us; speedup vs baseline: 2.3079x; 1.3743x over previous
//
#include <hip/hip_runtime.h>
#include <utility>

typedef __attribute__((ext_vector_type(8))) short short8;
typedef __attribute__((ext_vector_type(4))) float f32x4;

#define T_   512
#define B_   64
#define I_   256
#define H_   512
#define BH   (B_*H_)   // 32768
#define NB0  32
#define NBT  64

// ---- ws layout (bytes) ----
#define WS_XB   0u            // bf16 X        [512][64][256]   16,777,216
#define WS_HS   16777216u     // bf16 hs ring  [513][64][512]   33,619,968
#define WS_H1   50397184u     // bf16 h1 dbuf  [2][64][512]        131,072
#define WS_P0   50528256u     // packed W0cat  (3 MB)
#define WS_P1   53673984u     // packed W1cat  (4 MB)
#define WS_B0   57868288u     // f32 bias0 [2048]
#define WS_B1   57876480u     // f32 bias1 [2048]
#define WS_BAR  57884672u     // 64 x u32 flags, 64B apart (4 KB)

__device__ __forceinline__ unsigned short f2b(float f) {
    unsigned int x = __builtin_bit_cast(unsigned int, f);
    unsigned int r = (x + 0x7fffu + ((x >> 16) & 1u)) >> 16;   // RNE
    return (unsigned short)r;
}

// ---- coherent (cross-XCD, L2-bypass) access primitives ----
template<int OFF>
__device__ __forceinline__ short8 ldc16(const unsigned short* p) {
    short8 r;
    asm volatile("global_load_dwordx4 %0, %1, off offset:%c2 sc0 sc1"
                 : "=v"(r) : "v"(p), "i"(OFF));
    return r;
}
template<int... I>
__device__ __forceinline__ void ldbatch(short8* av, const unsigned short* p,
                                        std::integer_sequence<int, I...>) {
    ((av[I] = ldc16<I * 64>(p)), ...);
}
__device__ __forceinline__ void stc16(unsigned short* p, unsigned short v) {
    unsigned vv = v;
    asm volatile("global_store_short %0, %1, off sc0 sc1" :: "v"(p), "v"(vv) : "memory");
}
__device__ __forceinline__ void stc32(unsigned* p, unsigned v) {
    asm volatile("global_store_dword %0, %1, off sc0 sc1" :: "v"(p), "v"(v) : "memory");
}
__device__ __forceinline__ unsigned ldc32(const unsigned* p) {
    unsigned v;
    asm volatile("global_load_dword %0, %1, off sc0 sc1\n\ts_waitcnt vmcnt(0)"
                 : "=v"(v) : "v"(p) : "memory");
    return v;
}
#define VMWAIT0  do { asm volatile("s_waitcnt vmcnt(0)"  ::: "memory"); __builtin_amdgcn_sched_barrier(0); } while (0)
#define VMWAIT16 do { asm volatile("s_waitcnt vmcnt(16)" ::: "memory"); __builtin_amdgcn_sched_barrier(0); } while (0)

// arrive: drain own stores to coherent point, block-sync, publish generation (no RMW)
__device__ __forceinline__ void bar_arrive(unsigned* bar, int bid, unsigned gen) {
    asm volatile("s_waitcnt vmcnt(0)" ::: "memory");
    __syncthreads();
    if (threadIdx.x == 0) stc32(&bar[bid * 16], gen);
}
// wait until flags of blocks [0, nb) all >= gen; wave 0 polls lane-parallel
__device__ __forceinline__ void bar_wait(const unsigned* bar, int nb, unsigned gen) {
    if (threadIdx.x < 64) {
        const unsigned* p = &bar[(int)threadIdx.x * 16];
        const bool need = (int)threadIdx.x < nb;
        for (;;) {
            unsigned v = ldc32(p);
            if (__all(!need || v >= gen)) break;
        }
    }
    __syncthreads();
}

// X f32 -> bf16, and copy inputs to output tail (outputs: h_n|c_n|inputs)
__global__ void convert_x(const float* __restrict__ X, unsigned short* __restrict__ Xb,
                          float* __restrict__ outcpy) {
    const int n4 = (T_ * B_ * I_) / 4;
    for (int i = blockIdx.x * blockDim.x + threadIdx.x; i < n4; i += gridDim.x * blockDim.x) {
        float4 v = reinterpret_cast<const float4*>(X)[i];
        ushort4 u;
        u.x = f2b(v.x); u.y = f2b(v.y); u.z = f2b(v.z); u.w = f2b(v.w);
        reinterpret_cast<ushort4*>(Xb)[i] = u;
        reinterpret_cast<float4*>(outcpy)[i] = v;
    }
}

// Pack Wcat0 = [Wih0 | Whh0] (K=768) into 16x16x32 B-fragment order.
__global__ void pack_w0(const float* __restrict__ Wih, const float* __restrict__ Whh,
                        unsigned short* __restrict__ p0) {
    const int n = 32 * 4 * 24 * 64;
    int idx = blockIdx.x * blockDim.x + threadIdx.x;
    if (idx >= n) return;
    int lane = idx & 63; int q = idx >> 6;
    int ks = q % 24; q /= 24;
    int g = q & 3;   int j = q >> 2;
    int row_w = g * 512 + j * 16 + (lane & 15);
    int k0 = ks * 32 + (lane >> 4) * 8;
    short8 o;
#pragma unroll
    for (int e = 0; e < 8; e++) {
        int k = k0 + e;
        float v = (k < 256) ? Wih[row_w * 256 + k] : Whh[row_w * 512 + (k - 256)];
        o[e] = (short)f2b(v);
    }
    reinterpret_cast<short8*>(p0)[idx] = o;
}

// Wcat1 = [Wih1 | Whh1] (K=1024), 32 k-steps
__global__ void pack_w1(const float* __restrict__ Wih, const float* __restrict__ Whh,
                        unsigned short* __restrict__ p1) {
    const int n = 32 * 4 * 32 * 64;
    int idx = blockIdx.x * blockDim.x + threadIdx.x;
    if (idx >= n) return;
    int lane = idx & 63; int q = idx >> 6;
    int ks = q & 31; q >>= 5;
    int g = q & 3;   int j = q >> 2;
    int row_w = g * 512 + j * 16 + (lane & 15);
    int k0 = ks * 32 + (lane >> 4) * 8;
    short8 o;
#pragma unroll
    for (int e = 0; e < 8; e++) {
        int k = k0 + e;
        float v = (k < 512) ? Wih[row_w * 512 + k] : Whh[row_w * 512 + (k - 512)];
        o[e] = (short)f2b(v);
    }
    reinterpret_cast<short8*>(p1)[idx] = o;
}

// combined biases + initial h states (bf16) + barrier flags zero
__global__ void prep_misc(const float* __restrict__ bih0, const float* __restrict__ bhh0,
                          const float* __restrict__ bih1, const float* __restrict__ bhh1,
                          const float* __restrict__ h0,
                          float* __restrict__ b0c, float* __restrict__ b1c,
                          unsigned short* __restrict__ hs, unsigned short* __restrict__ h1b,
                          unsigned* __restrict__ bar) {
    int i = blockIdx.x * blockDim.x + threadIdx.x;
    if (i < 1024) __hip_atomic_store(&bar[i], 0u, __ATOMIC_RELAXED, __HIP_MEMORY_SCOPE_AGENT);
    if (i < 2048) b0c[i] = bih0[i] + bhh0[i];
    else if (i < 4096) { int k = i - 2048; b1c[k] = bih1[k] + bhh1[k]; }
    else if (i < 4096 + BH) { int k = i - 4096; hs[k] = f2b(h0[k]); }
    else if (i < 4096 + 2 * BH) { int k = i - 4096 - BH; h1b[k] = f2b(h0[BH + k]); }
}

// Persistent pipelined LSTM: 64 blocks x 256 threads.
// Blocks 0..31: layer 0 (block j owns h-cols j*16..+15); wait only on L0 flags.
// Blocks 32..63: layer 1, one step behind; wait on all flags.
__global__ void __launch_bounds__(256, 1) lstm_pers(
    const unsigned short* __restrict__ Xb,
    unsigned short* __restrict__ hs,
    unsigned short* __restrict__ h1b,
    const unsigned short* __restrict__ p0,
    const unsigned short* __restrict__ p1,
    const float* __restrict__ b0c,
    const float* __restrict__ b1c,
    const float* __restrict__ c0,
    float* __restrict__ out,
    unsigned* __restrict__ bar) {
    __shared__ __align__(16) unsigned short bsh[65536];   // up to 128 KB packed-W slice

    const int bid = blockIdx.x;
    const int tid = threadIdx.x;
    const int lane = tid & 63;
    const int w = tid >> 6;
    const int la = lane & 15;      // A-row / D-col within tile
    const int lk = lane >> 4;      // k-subgroup; D-rows = lk*4+reg
    const int hc = la;

    if (bid < NB0) {
        // ================= layer 0 =================
        const int j = bid;
        {
            const short8* src = reinterpret_cast<const short8*>(p0 + (size_t)j * 49152);
            short8* dst = reinterpret_cast<short8*>(bsh);
            for (int i = tid; i < 6144; i += 256) dst[i] = src[i];
        }
        __syncthreads();

        const float bi = b0c[       j * 16 + hc];
        const float bf = b0c[512  + j * 16 + hc];
        const float bg = b0c[1024 + j * 16 + hc];
        const float bo = b0c[1536 + j * 16 + hc];
        float c[4];
#pragma unroll
        for (int r = 0; r < 4; r++) c[r] = c0[(w * 16 + lk * 4 + r) * 512 + j * 16 + hc];

        // x-part for step 0 (plain loads, Xb is read-only kernel input data)
        f32x4 a0 = {0.f,0.f,0.f,0.f}, a1 = a0, a2 = a0, a3 = a0;
        {
            const unsigned short* Arow_x = Xb + (size_t)(w * 16 + la) * 256 + lk * 8;
#pragma unroll
            for (int ks = 0; ks < 8; ks++) {
                short8 av = *reinterpret_cast<const short8*>(Arow_x + ks * 32);
                const unsigned short* bb = bsh + ks * 512 + lane * 8;
                a0 = __builtin_amdgcn_mfma_f32_16x16x32_bf16(av, *reinterpret_cast<const short8*>(bb            ), a0, 0, 0, 0);
                a1 = __builtin_amdgcn_mfma_f32_16x16x32_bf16(av, *reinterpret_cast<const short8*>(bb + 24 * 512), a1, 0, 0, 0);
                a2 = __builtin_amdgcn_mfma_f32_16x16x32_bf16(av, *reinterpret_cast<const short8*>(bb + 48 * 512), a2, 0, 0, 0);
                a3 = __builtin_amdgcn_mfma_f32_16x16x32_bf16(av, *reinterpret_cast<const short8*>(bb + 72 * 512), a3, 0, 0, 0);
            }
        }

        for (int n = 0; n < T_; n++) {
            if (n > 0) bar_wait(bar, NB0, (unsigned)n);
            // critical h-part: K=512 over hs[n], coherent A loads
            short8 av[16];
            const unsigned short* Arow_h = hs + (size_t)n * BH + (size_t)(w * 16 + la) * 512 + lk * 8;
            ldbatch(av, Arow_h, std::make_integer_sequence<int, 16>{});
            VMWAIT0;
#pragma unroll
            for (int ks = 0; ks < 16; ks++) {
                const unsigned short* bb = bsh + (8 + ks) * 512 + lane * 8;
                a0 = __builtin_amdgcn_mfma_f32_16x16x32_bf16(av[ks], *reinterpret_cast<const short8*>(bb            ), a0, 0, 0, 0);
                a1 = __builtin_amdgcn_mfma_f32_16x16x32_bf16(av[ks], *reinterpret_cast<const short8*>(bb + 24 * 512), a1, 0, 0, 0);
                a2 = __builtin_amdgcn_mfma_f32_16x16x32_bf16(av[ks], *reinterpret_cast<const short8*>(bb + 48 * 512), a2, 0, 0, 0);
                a3 = __builtin_amdgcn_mfma_f32_16x16x32_bf16(av[ks], *reinterpret_cast<const short8*>(bb + 72 * 512), a3, 0, 0, 0);
            }
#pragma unroll
            for (int r = 0; r < 4; r++) {
                float ip = a0[r] + bi, fp = a1[r] + bf, gp = a2[r] + bg, op = a3[r] + bo;
                float si = 1.f / (1.f + __expf(-ip));
                float sf = 1.f / (1.f + __expf(-fp));
                float so = 1.f / (1.f + __expf(-op));
                float tg = tanhf(gp);
                float cn = sf * c[r] + si * tg;
                float hn = so * tanhf(cn);
                c[r] = cn;
                int row = w * 16 + lk * 4 + r;
                stc16(hs + (size_t)(n + 1) * BH + row * 512 + j * 16 + hc, f2b(hn));
                if (n == T_ - 1) {
                    out[row * 512 + j * 16 + hc] = hn;            // h_n[0]
                    out[65536 + row * 512 + j * 16 + hc] = cn;    // c_n[0]
                }
            }
            bar_arrive(bar, bid, (unsigned)(n + 1));
            if (n < T_ - 1) {   // hidden x-part for step n+1, off critical path
                f32x4 z = {0.f,0.f,0.f,0.f};
                a0 = z; a1 = z; a2 = z; a3 = z;
                const unsigned short* Arow_x = Xb + ((size_t)(n + 1) * B_ + w * 16 + la) * 256 + lk * 8;
#pragma unroll
                for (int ks = 0; ks < 8; ks++) {
                    short8 av2 = *reinterpret_cast<const short8*>(Arow_x + ks * 32);
                    const unsigned short* bb = bsh + ks * 512 + lane * 8;
                    a0 = __builtin_amdgcn_mfma_f32_16x16x32_bf16(av2, *reinterpret_cast<const short8*>(bb            ), a0, 0, 0, 0);
                    a1 = __builtin_amdgcn_mfma_f32_16x16x32_bf16(av2, *reinterpret_cast<const short8*>(bb + 24 * 512), a1, 0, 0, 0);
                    a2 = __builtin_amdgcn_mfma_f32_16x16x32_bf16(av2, *reinterpret_cast<const short8*>(bb + 48 * 512), a2, 0, 0, 0);
                    a3 = __builtin_amdgcn_mfma_f32_16x16x32_bf16(av2, *reinterpret_cast<const short8*>(bb + 72 * 512), a3, 0, 0, 0);
                }
            }
        }
    } else {
        // ================= layer 1 (one step behind) =================
        const int j = bid - NB0;
        {
            const short8* src = reinterpret_cast<const short8*>(p1 + (size_t)j * 65536);
            short8* dst = reinterpret_cast<short8*>(bsh);
            for (int i = tid; i < 8192; i += 256) dst[i] = src[i];
        }
        __syncthreads();

        const float bi = b1c[       j * 16 + hc];
        const float bf = b1c[512  + j * 16 + hc];
        const float bg = b1c[1024 + j * 16 + hc];
        const float bo = b1c[1536 + j * 16 + hc];
        float c[4];
#pragma unroll
        for (int r = 0; r < 4; r++) c[r] = c0[BH + (w * 16 + lk * 4 + r) * 512 + j * 16 + hc];

#define L1_STEP(s, FINAL)                                                                              \
        {                                                                                              \
            short8 av0[16], av1[16];                                                                   \
            const unsigned short* Arow_x = hs + (size_t)((s) + 1) * BH + (size_t)(w * 16 + la) * 512 + lk * 8; \
            const unsigned short* Arow_h = h1b + (size_t)((s) & 1) * BH + (size_t)(w * 16 + la) * 512 + lk * 8; \
            ldbatch(av0, Arow_x, std::make_integer_sequence<int, 16>{});                               \
            ldbatch(av1, Arow_h, std::make_integer_sequence<int, 16>{});                               \
            f32x4 z = {0.f,0.f,0.f,0.f};                                                               \
            f32x4 a0 = z, a1 = z, a2 = z, a3 = z;                                                      \
            VMWAIT16;                                                                                  \
            _Pragma("unroll")                                                                          \
            for (int ks = 0; ks < 16; ks++) {                                                          \
                const unsigned short* bb = bsh + ks * 512 + lane * 8;                                  \
                a0 = __builtin_amdgcn_mfma_f32_16x16x32_bf16(av0[ks], *reinterpret_cast<const short8*>(bb            ), a0, 0, 0, 0); \
                a1 = __builtin_amdgcn_mfma_f32_16x16x32_bf16(av0[ks], *reinterpret_cast<const short8*>(bb + 32 * 512), a1, 0, 0, 0); \
                a2 = __builtin_amdgcn_mfma_f32_16x16x32_bf16(av0[ks], *reinterpret_cast<const short8*>(bb + 64 * 512), a2, 0, 0, 0); \
                a3 = __builtin_amdgcn_mfma_f32_16x16x32_bf16(av0[ks], *reinterpret_cast<const short8*>(bb + 96 * 512), a3, 0, 0, 0); \
            }                                                                                          \
            VMWAIT0;                                                                                   \
            _Pragma("unroll")                                                                          \
            for (int ks = 0; ks < 16; ks++) {                                                          \
                const unsigned short* bb = bsh + (16 + ks) * 512 + lane * 8;                           \
                a0 = __builtin_amdgcn_mfma_f32_16x16x32_bf16(av1[ks], *reinterpret_cast<const short8*>(bb            ), a0, 0, 0, 0); \
                a1 = __builtin_amdgcn_mfma_f32_16x16x32_bf16(av1[ks], *reinterpret_cast<const short8*>(bb + 32 * 512), a1, 0, 0, 0); \
                a2 = __builtin_amdgcn_mfma_f32_16x16x32_bf16(av1[ks], *reinterpret_cast<const short8*>(bb + 64 * 512), a2, 0, 0, 0); \
                a3 = __builtin_amdgcn_mfma_f32_16x16x32_bf16(av1[ks], *reinterpret_cast<const short8*>(bb + 96 * 512), a3, 0, 0, 0); \
            }                                                                                          \
            _Pragma("unroll")                                                                          \
            for (int r = 0; r < 4; r++) {                                                              \
                float ip = a0[r] + bi, fp = a1[r] + bf, gp = a2[r] + bg, op = a3[r] + bo;              \
                float si = 1.f / (1.f + __expf(-ip));                                                  \
                float sf = 1.f / (1.f + __expf(-fp));                                                  \
                float so = 1.f / (1.f + __expf(-op));                                                  \
                float tg = tanhf(gp);                                                                  \
                float cn = sf * c[r] + si * tg;                                                        \
                float hn = so * tanhf(cn);                                                             \
                c[r] = cn;                                                                             \
                int row = w * 16 + lk * 4 + r;                                                         \
                if (!(FINAL)) {                                                                        \
                    stc16(h1b + (size_t)(((s) + 1) & 1) * BH + row * 512 + j * 16 + hc, f2b(hn));      \
                } else {                                                                               \
                    out[BH + row * 512 + j * 16 + hc] = hn;                                            \
                    out[65536 + BH + row * 512 + j * 16 + hc] = cn;                                    \
                }                                                                                      \
            }                                                                                          \
        }

        for (int n = 0; n < T_; n++) {
            if (n > 0) {
                bar_wait(bar, NBT, (unsigned)n);
                L1_STEP(n - 1, 0)
            }
            bar_arrive(bar, bid, (unsigned)(n + 1));
        }
        bar_wait(bar, NBT, (unsigned)T_);
        L1_STEP(T_ - 1, 1)
    }
}

extern "C" void kernel_launch(void* const* d_in, const int* in_sizes, int n_in,
                              void* d_out, int out_size, void* d_ws, size_t ws_size,
                              hipStream_t stream) {
    const float* X    = (const float*)d_in[0];
    const float* h0   = (const float*)d_in[1];
    const float* c0   = (const float*)d_in[2];
    const float* wih0 = (const float*)d_in[3];
    const float* whh0 = (const float*)d_in[4];
    const float* bih0 = (const float*)d_in[5];
    const float* bhh0 = (const float*)d_in[6];
    const float* wih1 = (const float*)d_in[7];
    const float* whh1 = (const float*)d_in[8];
    const float* bih1 = (const float*)d_in[9];
    const float* bhh1 = (const float*)d_in[10];
    float* out = (float*)d_out;
    char* ws = (char*)d_ws;

    unsigned short* Xb  = (unsigned short*)(ws + WS_XB);
    unsigned short* hsb = (unsigned short*)(ws + WS_HS);
    unsigned short* h1b = (unsigned short*)(ws + WS_H1);
    unsigned short* p0  = (unsigned short*)(ws + WS_P0);
    unsigned short* p1  = (unsigned short*)(ws + WS_P1);
    float* b0c = (float*)(ws + WS_B0);
    float* b1c = (float*)(ws + WS_B1);
    unsigned* bar = (unsigned*)(ws + WS_BAR);

    hipLaunchKernelGGL(convert_x, dim3(2048), dim3(256), 0, stream, X, Xb, out + 131072);
    hipLaunchKernelGGL(pack_w0, dim3(768), dim3(256), 0, stream, wih0, whh0, p0);
    hipLaunchKernelGGL(pack_w1, dim3(1024), dim3(256), 0, stream, wih1, whh1, p1);
    hipLaunchKernelGGL(prep_misc, dim3(276), dim3(256), 0, stream,
                       bih0, bhh0, bih1, bhh1, h0, b0c, b1c, hsb, h1b, bar);
    hipLaunchKernelGGL(lstm_pers, dim3(NBT), dim3(256), 0, stream,
                       Xb, hsb, h1b, p0, p1, b0c, b1c, c0, out, bar);
}